// Round 4
// baseline (172.418 us; speedup 1.0000x reference)
//
#include <hip/hip_runtime.h>

#define KTAGS 11
#define SS    13
#define TT    1024
#define BB    4096
#define CPW   16     // chains per wave (4 lanes per chain)
#define PF    8      // prefetch depth (register pipeline), 4 VMEM loads/step -> 32 in flight

// Quad-perm DPP broadcast: value of lane (4k+Q) to all 4 lanes of quad k. VALU-speed.
#define QBC(x, Q) __uint_as_float((unsigned)__builtin_amdgcn_update_dpp( \
      0, (int)__float_as_uint(x), ((Q)*0x55), 0xF, 0xF, false))
// Quad butterfly patterns for exact 4-lane sums: [1,0,3,2]=0xB1, [2,3,0,1]=0x4E
#define QSW1(x) __uint_as_float((unsigned)__builtin_amdgcn_update_dpp( \
      0, (int)__float_as_uint(x), 0xB1, 0xF, 0xF, false))
#define QSW2(x) __uint_as_float((unsigned)__builtin_amdgcn_update_dpp( \
      0, (int)__float_as_uint(x), 0x4E, 0xF, 0xF, false))

__global__ __launch_bounds__(64)
void crf_scan_kernel(const float* __restrict__ e,
                     const float* __restrict__ Tmat,
                     const int*   __restrict__ tags,
                     float*       __restrict__ out_per_b)
{
    __shared__ float sT[SS * SS];
    const int tid = threadIdx.x;
    for (int i = tid; i < SS * SS; i += 64) sT[i] = Tmat[i];
    __syncthreads();

    const int q  = tid & 3;          // lane within quad
    const int ci = tid >> 2;         // chain within wave
    const int b  = blockIdx.x * CPW + ci;
    const int OB = 3 * q;            // my output base (q=3 -> 9,10,[11=dummy zero col])
    const int c0 = OB, c1 = OB + 1;
    const int c2 = (OB + 2 < KTAGS) ? OB + 2 : KTAGS - 1;   // clamped e-load column

    // My 3 columns of M = exp(Tmat): M?[f] = exp(T[f][OB+?]). Column 11 (START) -> exp(NEG)=0.
    float M0[KTAGS], M1[KTAGS], M2[KTAGS];
#pragma unroll
    for (int f = 0; f < KTAGS; ++f) {
        M0[f] = __expf(sT[f * SS + OB]);
        M1[f] = __expf(sT[f * SS + OB + 1]);
        M2[f] = __expf(sT[f * SS + OB + 2]);
    }
    const float es0 = __expf(sT[(OB)     * SS + (SS - 1)]);
    const float es1 = __expf(sT[(OB + 1) * SS + (SS - 1)]);
    const float es2 = __expf(sT[(OB + 2) * SS + (SS - 1)]);

    const float* ebase = e + (size_t)b * TT * KTAGS;
    const float* pe0 = ebase + c0;
    const float* pe1 = ebase + c1;
    const float* pe2 = ebase + c2;
    const int*   tgp = tags + (size_t)b * TT;

    // ---------------- t = 0 ----------------
    const float E00 = pe0[0], E10 = pe1[0], E20 = pe2[0];
    int tg_prev = tgp[0];
    float a0 = __expf(sT[(SS - 2) * SS + OB]     + E00);
    float a1 = __expf(sT[(SS - 2) * SS + OB + 1] + E10);
    float a2 = __expf(sT[(SS - 2) * SS + OB + 2] + E20);   // q=3: exp(NEG+x)=0

    float cacc = 0.f;
    const float gold0 = sT[(SS - 2) * SS + tg_prev];
    float em_acc = (tg_prev == c0) ? E00 : (tg_prev == c1) ? E10
                 : (tg_prev == OB + 2) ? E20 : 0.f;
    float trans_acc = 0.f, trv = 0.f;

    // ---------------- register prefetch pipeline ----------------
    float eb0[PF], eb1[PF], eb2[PF], xb0[PF], xb1[PF], xb2[PF];
    int   tb_[PF];
#pragma unroll
    for (int j = 0; j < PF; ++j) {
        eb0[j] = pe0[(size_t)(1 + j) * KTAGS];
        eb1[j] = pe1[(size_t)(1 + j) * KTAGS];
        eb2[j] = pe2[(size_t)(1 + j) * KTAGS];
        tb_[j] = tgp[1 + j];
    }

    float scP = 1.f, eeP = 0.f;   // delayed power-of-two rescale (exact)

// t = tb + J with tb % 4 == 1: apply pending rescale at (J&3)==0 (t%4==1),
// compute new pending at (J&3)==3 (t%4==0), from the pre-update alphas (g's).
#define STEP(J, E0v, E1v, E2v, X0v, X1v, X2v, TG)                              \
    {                                                                          \
        const float g0 = QBC(a0,0), g1 = QBC(a1,0), g2 = QBC(a2,0);            \
        const float g3 = QBC(a0,1), g4 = QBC(a1,1), g5 = QBC(a2,1);            \
        const float g6 = QBC(a0,2), g7 = QBC(a1,2), g8 = QBC(a2,2);            \
        const float g9 = QBC(a0,3), g10 = QBC(a1,3);                           \
        float s0 = X0v, s1 = X1v, s2 = X2v;                                    \
        if (((J) & 3) == 0) { cacc += eeP * 0.6931471805599453f;               \
                              s0 *= scP; s1 *= scP; s2 *= scP; }               \
        float dA0 = g0*M0[0],  dB0 = g1*M0[1];                                 \
        float dA1 = g0*M1[0],  dB1 = g1*M1[1];                                 \
        float dA2 = g0*M2[0],  dB2 = g1*M2[1];                                 \
        dA0 = fmaf(g2,M0[2],dA0); dB0 = fmaf(g3,M0[3],dB0);                    \
        dA1 = fmaf(g2,M1[2],dA1); dB1 = fmaf(g3,M1[3],dB1);                    \
        dA2 = fmaf(g2,M2[2],dA2); dB2 = fmaf(g3,M2[3],dB2);                    \
        dA0 = fmaf(g4,M0[4],dA0); dB0 = fmaf(g5,M0[5],dB0);                    \
        dA1 = fmaf(g4,M1[4],dA1); dB1 = fmaf(g5,M1[5],dB1);                    \
        dA2 = fmaf(g4,M2[4],dA2); dB2 = fmaf(g5,M2[5],dB2);                    \
        dA0 = fmaf(g6,M0[6],dA0); dB0 = fmaf(g7,M0[7],dB0);                    \
        dA1 = fmaf(g6,M1[6],dA1); dB1 = fmaf(g7,M1[7],dB1);                    \
        dA2 = fmaf(g6,M2[6],dA2); dB2 = fmaf(g7,M2[7],dB2);                    \
        dA0 = fmaf(g8,M0[8],dA0); dB0 = fmaf(g9,M0[9],dB0);                    \
        dA1 = fmaf(g8,M1[8],dA1); dB1 = fmaf(g9,M1[9],dB1);                    \
        dA2 = fmaf(g8,M2[8],dA2); dB2 = fmaf(g9,M2[9],dB2);                    \
        dA0 = fmaf(g10,M0[10],dA0);                                            \
        dA1 = fmaf(g10,M1[10],dA1);                                            \
        dA2 = fmaf(g10,M2[10],dA2);                                            \
        if (((J) & 3) == 3) {                                                  \
            float mm = fmaxf(fmaxf(fmaxf(g0,g1),fmaxf(g2,g3)),                 \
                      fmaxf(fmaxf(fmaxf(g4,g5),fmaxf(g6,g7)),                  \
                            fmaxf(fmaxf(g8,g9),g10)));                         \
            const int ee = (int)((__float_as_uint(mm) >> 23) & 0xFFu) - 127;   \
            scP = __uint_as_float((unsigned)(127 - ee) << 23);                 \
            eeP = (float)ee;                                                   \
        }                                                                      \
        a0 = (dA0 + dB0) * s0;                                                 \
        a1 = (dA1 + dB1) * s1;                                                 \
        a2 = (dA2 + dB2) * s2;                                                 \
        em_acc    += ((TG) == c0) ? (E0v) : ((TG) == c1) ? (E1v)               \
                   : ((TG) == OB + 2) ? (E2v) : 0.f;                           \
        trans_acc += trv;                     /* prev step's lookup */         \
        trv = sT[tg_prev * SS + (TG)];        /* 1-step pipelined ds_read */   \
        tg_prev = (TG);                                                        \
    }

    const float* q0 = pe0 + (size_t)(1 + PF) * KTAGS;
    const float* q1 = pe1 + (size_t)(1 + PF) * KTAGS;
    const float* q2 = pe2 + (size_t)(1 + PF) * KTAGS;
    const int*   qt = tgp + 1 + PF;

    int tb = 1;
    for (; tb + 2 * PF <= TT; tb += PF) {   // tb = 1..1001: steps 1..1008, prefetch <= 1016
#pragma unroll
        for (int k = 0; k < PF; ++k) {
            xb0[k] = __expf(eb0[k]); xb1[k] = __expf(eb1[k]); xb2[k] = __expf(eb2[k]);
        }
#pragma unroll
        for (int j = 0; j < PF; ++j) {
            const float E0v = eb0[j], E1v = eb1[j], E2v = eb2[j];
            const float X0v = xb0[j], X1v = xb1[j], X2v = xb2[j];
            const int   TG  = tb_[j];
            eb0[j] = q0[j * KTAGS]; eb1[j] = q1[j * KTAGS]; eb2[j] = q2[j * KTAGS];
            tb_[j] = qt[j];
            STEP(j, E0v, E1v, E2v, X0v, X1v, X2v, TG)
        }
        q0 += PF * KTAGS; q1 += PF * KTAGS; q2 += PF * KTAGS; qt += PF;
    }

    // penultimate block: tb == 1009 (steps 1009..1016), prefetch only 7 (t = 1017..1023)
#pragma unroll
    for (int k = 0; k < PF; ++k) {
        xb0[k] = __expf(eb0[k]); xb1[k] = __expf(eb1[k]); xb2[k] = __expf(eb2[k]);
    }
#pragma unroll
    for (int j = 0; j < PF; ++j) {
        const float E0v = eb0[j], E1v = eb1[j], E2v = eb2[j];
        const float X0v = xb0[j], X1v = xb1[j], X2v = xb2[j];
        const int   TG  = tb_[j];
        if (j < PF - 1) {
            eb0[j] = q0[j * KTAGS]; eb1[j] = q1[j * KTAGS]; eb2[j] = q2[j * KTAGS];
            tb_[j] = qt[j];
        }
        STEP(j, E0v, E1v, E2v, X0v, X1v, X2v, TG)
    }

    // tail: steps t = 1017..1023 from slots 0..6
#pragma unroll
    for (int k = 0; k < PF - 1; ++k) {
        xb0[k] = __expf(eb0[k]); xb1[k] = __expf(eb1[k]); xb2[k] = __expf(eb2[k]);
    }
#pragma unroll
    for (int j = 0; j < PF - 1; ++j) {
        STEP(j, eb0[j], eb1[j], eb2[j], xb0[j], xb1[j], xb2[j], tb_[j])
    }
#undef STEP

    // ---------------- epilogue ----------------
    trans_acc += trv;   // last pending transition (1022 -> 1023)

    float zp = a0 * es0 + a1 * es1 + a2 * es2;
    zp += QSW1(zp); zp += QSW2(zp);            // exact quad sum, all lanes identical
    float em = em_acc;
    em += QSW1(em); em += QSW2(em);

    if (q == 0) {
        const float logZ = cacc + __logf(zp);
        const float gold = gold0 + em + trans_acc + sT[tg_prev * SS + (SS - 1)];
        out_per_b[b] = logZ - gold;
    }
}

// Deterministic mean over B values (double accumulation).
__global__ __launch_bounds__(256)
void reduce_mean_kernel(const float* __restrict__ v, float* __restrict__ out, int n)
{
    __shared__ double sbuf[256];
    double s = 0.0;
    for (int i = threadIdx.x; i < n; i += 256) s += (double)v[i];
    sbuf[threadIdx.x] = s;
    __syncthreads();
    for (int k = 128; k > 0; k >>= 1) {
        if ((int)threadIdx.x < k) sbuf[threadIdx.x] += sbuf[threadIdx.x + k];
        __syncthreads();
    }
    if (threadIdx.x == 0) out[0] = (float)(sbuf[0] / (double)n);
}

extern "C" void kernel_launch(void* const* d_in, const int* in_sizes, int n_in,
                              void* d_out, int out_size, void* d_ws, size_t ws_size,
                              hipStream_t stream)
{
    const float* e    = (const float*)d_in[0];
    const float* Tmat = (const float*)d_in[1];
    const int*   tags = (const int*)d_in[2];
    // d_in[3] = mask: all-true in this problem; kernel implements the all-true path.

    float* ws  = (float*)d_ws;       // BB floats of scratch
    float* out = (float*)d_out;

    crf_scan_kernel<<<BB / CPW, 64, 0, stream>>>(e, Tmat, tags, ws);
    reduce_mean_kernel<<<1, 256, 0, stream>>>(ws, out, BB);
}

// Round 5
// 137.445 us; speedup vs baseline: 1.2544x; 1.2544x over previous
//
#include <hip/hip_runtime.h>

#define KTAGS 11
#define SS    13
#define TT    1024
#define BB    4096
#define GPW   4      // chains per 64-thread block (16 lanes per chain)
#define PF    16     // prefetch pipeline depth

// DPP row_ror:r within the 16-lane row: dst[l] = src[(l - r) & 15]. VALU-speed.
#define ROR(x, r) __uint_as_float((unsigned)__builtin_amdgcn_update_dpp( \
      0, (int)__float_as_uint(x), (0x120 | (r)), 0xF, 0xF, false))

__global__ __launch_bounds__(64)
void crf_scan_kernel(const float* __restrict__ e,
                     const float* __restrict__ Tmat,
                     const int*   __restrict__ tags,
                     float*       __restrict__ out_per_b)
{
    __shared__ float sT[SS * SS];
    const int tid = threadIdx.x;
    for (int i = tid; i < SS * SS; i += 64) sT[i] = Tmat[i];

    const int g   = tid >> 4;          // chain within wave
    const int to  = tid & 15;          // state owned by lane (0..10 real, 11..15 pad)
    const int toT = (to < SS) ? to : (SS - 1);       // clamped T column
    const int toE = (to < KTAGS) ? to : (KTAGS - 1); // clamped e column
    const int b   = blockIdx.x * GPW + g;

    __syncthreads();   // sT staged (only barrier)

    // Rotation-indexed M: W[r] multiplies ror_r(alpha) = alpha[(to - r) & 15].
    // W[r] = exp(T[f][to]) for f=(to-r)&15 when f<11 and to<=12; else exactly 0.
    float W[16];
#pragma unroll
    for (int r = 0; r < 16; ++r) {
        const int f = (to - r) & 15;
        W[r] = (f < KTAGS && to <= SS - 1 && to != KTAGS)   // to==11 (START col) -> 0 anyway
                 ? __expf(sT[f * SS + toT]) : 0.f;
        if (to >= SS) W[r] = 0.f;       // lanes 13..15: stay identically zero
    }
    const float eTstop = __expf(sT[toT * SS + (SS - 1)]);

    const float* pe  = e    + (size_t)b * TT * KTAGS + toE;
    const int*   tgp = tags + (size_t)b * TT;

    // ---------------- t = 0 ----------------
    const float e0 = pe[0];
    int tg_prev = tgp[0];
    float aP = (to < SS) ? __expf(sT[(SS - 2) * SS + toT] + e0) : 0.f;  // lane11: exp(NEG+x)=0

    float cacc = 0.f;
    const float gold0 = sT[(SS - 2) * SS + tg_prev];
    float em_acc    = (to == tg_prev) ? e0 : 0.f;
    float trans_acc = 0.f;

    // ---------------- register prefetch pipeline ----------------
    float ebuf[PF], xbuf[PF];
    int   tbuf[PF];
#pragma unroll
    for (int j = 0; j < PF; ++j) {
        ebuf[j] = pe[(size_t)(1 + j) * KTAGS];
        tbuf[j] = tgp[1 + j];
    }

    float scP = 1.f, eeP = 0.f;   // delayed exact power-of-two rescale

// t = tb + J, tb % 4 == 1: apply pending rescale at (J&3)==0 (t%4==1),
// compute new pending at (J&3)==3 from the pre-update rotation temps.
#define STEP(J, E_T, X_T, TG)                                                  \
    {                                                                          \
        const float r1  = ROR(aP, 1),  r2  = ROR(aP, 2),  r3  = ROR(aP, 3);    \
        const float r4  = ROR(aP, 4),  r5  = ROR(aP, 5),  r6  = ROR(aP, 6);    \
        const float r7  = ROR(aP, 7),  r8  = ROR(aP, 8),  r9  = ROR(aP, 9);    \
        const float r10 = ROR(aP, 10), r11 = ROR(aP, 11), r12 = ROR(aP, 12);   \
        const float r13 = ROR(aP, 13), r14 = ROR(aP, 14), r15 = ROR(aP, 15);   \
        float xsc = X_T;                                                       \
        if (((J) & 3) == 0) { cacc += eeP * 0.6931471805599453f; xsc *= scP; } \
        float d0 = aP  * W[0],  d1 = r1  * W[1];                               \
        float d2 = r2  * W[2],  d3 = r3  * W[3];                               \
        d0 = fmaf(r4,  W[4],  d0);  d1 = fmaf(r5,  W[5],  d1);                 \
        d2 = fmaf(r6,  W[6],  d2);  d3 = fmaf(r7,  W[7],  d3);                 \
        d0 = fmaf(r8,  W[8],  d0);  d1 = fmaf(r9,  W[9],  d1);                 \
        d2 = fmaf(r10, W[10], d2);  d3 = fmaf(r11, W[11], d3);                 \
        d0 = fmaf(r12, W[12], d0);  d1 = fmaf(r13, W[13], d1);                 \
        d2 = fmaf(r14, W[14], d2);  d3 = fmaf(r15, W[15], d3);                 \
        if (((J) & 3) == 3) {                                                  \
            float m = fmaxf(fmaxf(fmaxf(fmaxf(aP, r1), fmaxf(r2, r3)),         \
                                  fmaxf(fmaxf(r4, r5), fmaxf(r6, r7))),        \
                            fmaxf(fmaxf(fmaxf(r8, r9), fmaxf(r10, r11)),       \
                                  fmaxf(fmaxf(r12, r13), fmaxf(r14, r15))));   \
            const int ee = (int)((__float_as_uint(m) >> 23) & 0xFFu) - 127;    \
            scP = __uint_as_float((unsigned)(127 - ee) << 23);                 \
            eeP = (float)ee;                                                   \
        }                                                                      \
        aP = ((d0 + d1) + (d2 + d3)) * xsc;                                    \
        em_acc    += (to == (TG)) ? (E_T) : 0.f;                               \
        trans_acc += sT[tg_prev * SS + (TG)];                                  \
        tg_prev    = (TG);                                                     \
    }

    const float* qe = pe  + (size_t)(1 + PF) * KTAGS;   // next-block prefetch source
    const int*   qt = tgp + 1 + PF;

    int tb = 1;
    for (; tb + 2 * PF <= TT; tb += PF) {   // steps 1..992
#pragma unroll
        for (int k = 0; k < PF; ++k) xbuf[k] = __expf(ebuf[k]);
#pragma unroll
        for (int j = 0; j < PF; ++j) {
            const float E_T = ebuf[j];
            const float X_T = xbuf[j];
            const int   TG  = tbuf[j];
            ebuf[j] = qe[j * KTAGS];        // compile-time offsets, pointer bumped per block
            tbuf[j] = qt[j];
            STEP(j, E_T, X_T, TG)
        }
        qe += (size_t)PF * KTAGS; qt += PF;
    }

    // penultimate block: steps 993..1008, prefetch only 15 (steps 1009..1023)
#pragma unroll
    for (int k = 0; k < PF; ++k) xbuf[k] = __expf(ebuf[k]);
#pragma unroll
    for (int j = 0; j < PF; ++j) {
        const float E_T = ebuf[j];
        const float X_T = xbuf[j];
        const int   TG  = tbuf[j];
        if (j < PF - 1) { ebuf[j] = qe[j * KTAGS]; tbuf[j] = qt[j]; }
        STEP(j, E_T, X_T, TG)
    }

    // tail: steps 1009..1023 from slots 0..14
#pragma unroll
    for (int k = 0; k < PF - 1; ++k) xbuf[k] = __expf(ebuf[k]);
#pragma unroll
    for (int j = 0; j < PF - 1; ++j) {
        STEP(j, ebuf[j], xbuf[j], tbuf[j])
    }
#undef STEP

    // ---------------- epilogue: 16-lane reductions ----------------
    float z  = (to < KTAGS) ? aP * eTstop : 0.f;
    float em = em_acc;
#pragma unroll
    for (int s = 8; s >= 1; s >>= 1) {
        z  += __shfl_xor(z,  s, 16);
        em += __shfl_xor(em, s, 16);
    }
    if (to == 0) {
        const float logZ = cacc + __logf(z);
        const float gold = gold0 + em + trans_acc + sT[tg_prev * SS + (SS - 1)];
        out_per_b[b] = logZ - gold;
    }
}

// Deterministic mean over B values (double accumulation).
__global__ __launch_bounds__(256)
void reduce_mean_kernel(const float* __restrict__ v, float* __restrict__ out, int n)
{
    __shared__ double sbuf[256];
    double s = 0.0;
    for (int i = threadIdx.x; i < n; i += 256) s += (double)v[i];
    sbuf[threadIdx.x] = s;
    __syncthreads();
    for (int k = 128; k > 0; k >>= 1) {
        if ((int)threadIdx.x < k) sbuf[threadIdx.x] += sbuf[threadIdx.x + k];
        __syncthreads();
    }
    if (threadIdx.x == 0) out[0] = (float)(sbuf[0] / (double)n);
}

extern "C" void kernel_launch(void* const* d_in, const int* in_sizes, int n_in,
                              void* d_out, int out_size, void* d_ws, size_t ws_size,
                              hipStream_t stream)
{
    const float* e    = (const float*)d_in[0];
    const float* Tmat = (const float*)d_in[1];
    const int*   tags = (const int*)d_in[2];
    // d_in[3] = mask: all-true in this problem; kernel implements the all-true path.

    float* ws  = (float*)d_ws;       // BB floats of scratch
    float* out = (float*)d_out;

    crf_scan_kernel<<<BB / GPW, 64, 0, stream>>>(e, Tmat, tags, ws);
    reduce_mean_kernel<<<1, 256, 0, stream>>>(ws, out, BB);
}

// Round 6
// 114.649 us; speedup vs baseline: 1.5039x; 1.1988x over previous
//
#include <hip/hip_runtime.h>

#define KTAGS 11
#define SS    13
#define TT    1024
#define BB    4096
#define GPW   4      // chains per 64-thread block (16 lanes per chain)
#define PF    8      // prefetch pipeline depth (1023 % 8 == 7 -> tail = PF-1)

__global__ __launch_bounds__(64)
void crf_scan_kernel(const float* __restrict__ e,
                     const float* __restrict__ Tmat,
                     const int*   __restrict__ tags,
                     float*       __restrict__ out_per_b)
{
    __shared__ float sT[SS * SS];
    const int tid = threadIdx.x;
    for (int i = tid; i < SS * SS; i += 64) sT[i] = Tmat[i];

    const int g   = tid >> 4;          // chain within wave
    const int to  = tid & 15;          // state owned by lane (0..10 real, 11..15 pad)
    const int toT = (to < SS) ? to : (SS - 1);       // clamped T column
    const int toE = (to < KTAGS) ? to : (KTAGS - 1); // clamped e column
    const int b   = blockIdx.x * GPW + g;

    __syncthreads();   // sT staged (only barrier)

    // Rotation-indexed M: W[r] multiplies ror_r(alpha)[to] = alpha[(to - r) & 15].
    // W[r] = exp(T[f][to]) with f = (to-r)&15, zero when f >= 11 or lane is pad.
    // (Verified correct in round 5: absmax 0.0.)
    float W[16];
#pragma unroll
    for (int r = 0; r < 16; ++r) {
        const int f = (to - r) & 15;
        W[r] = (f < KTAGS && to <= SS - 1 && to != KTAGS)
                 ? __expf(sT[f * SS + toT]) : 0.f;
        if (to >= SS) W[r] = 0.f;
    }
    const float eTstop = __expf(sT[toT * SS + (SS - 1)]);

    const float* pe  = e    + (size_t)b * TT * KTAGS + toE;
    const int*   tgp = tags + (size_t)b * TT;

    // ---------------- t = 0 ----------------
    const float e0 = pe[0];
    int tg_prev = tgp[0];
    float aP = (to < SS) ? __expf(sT[(SS - 2) * SS + toT] + e0) : 0.f;

    float cacc = 0.f;
    const float gold0 = sT[(SS - 2) * SS + tg_prev];
    float em_acc    = (to == tg_prev) ? e0 : 0.f;
    float trans_acc = 0.f;

    // ---------------- register prefetch pipeline ----------------
    float ebuf[PF];
    int   tbuf[PF];
#pragma unroll
    for (int j = 0; j < PF; ++j) {
        ebuf[j] = pe[(size_t)(1 + j) * KTAGS];
        tbuf[j] = tgp[1 + j];
    }

    float scP = 1.f, eeP = 0.f;   // delayed exact power-of-two rescale

// One fused rotate-multiply-accumulate block: 4 DPP muls + 12 DPP fmacs.
// s_nop 1 covers the VALU-write -> DPP-read hazard on aP.
#define STEP(J, E_T, TG)                                                       \
    {                                                                          \
        const float X_T = __expf(E_T);   /* issues early, hides under fmacs */ \
        float ac0, ac1, ac2, ac3;                                              \
        asm volatile(                                                          \
          "s_nop 1\n\t"                                                        \
          "v_mul_f32 %0, %4, %5\n\t"                                           \
          "v_mul_f32_dpp %1, %4, %6  row_ror:1  row_mask:0xf bank_mask:0xf\n\t"\
          "v_mul_f32_dpp %2, %4, %7  row_ror:2  row_mask:0xf bank_mask:0xf\n\t"\
          "v_mul_f32_dpp %3, %4, %8  row_ror:3  row_mask:0xf bank_mask:0xf\n\t"\
          "v_fmac_f32_dpp %0, %4, %9  row_ror:4  row_mask:0xf bank_mask:0xf\n\t"\
          "v_fmac_f32_dpp %1, %4, %10 row_ror:5  row_mask:0xf bank_mask:0xf\n\t"\
          "v_fmac_f32_dpp %2, %4, %11 row_ror:6  row_mask:0xf bank_mask:0xf\n\t"\
          "v_fmac_f32_dpp %3, %4, %12 row_ror:7  row_mask:0xf bank_mask:0xf\n\t"\
          "v_fmac_f32_dpp %0, %4, %13 row_ror:8  row_mask:0xf bank_mask:0xf\n\t"\
          "v_fmac_f32_dpp %1, %4, %14 row_ror:9  row_mask:0xf bank_mask:0xf\n\t"\
          "v_fmac_f32_dpp %2, %4, %15 row_ror:10 row_mask:0xf bank_mask:0xf\n\t"\
          "v_fmac_f32_dpp %3, %4, %16 row_ror:11 row_mask:0xf bank_mask:0xf\n\t"\
          "v_fmac_f32_dpp %0, %4, %17 row_ror:12 row_mask:0xf bank_mask:0xf\n\t"\
          "v_fmac_f32_dpp %1, %4, %18 row_ror:13 row_mask:0xf bank_mask:0xf\n\t"\
          "v_fmac_f32_dpp %2, %4, %19 row_ror:14 row_mask:0xf bank_mask:0xf\n\t"\
          "v_fmac_f32_dpp %3, %4, %20 row_ror:15 row_mask:0xf bank_mask:0xf\n\t"\
          : "=&v"(ac0), "=&v"(ac1), "=&v"(ac2), "=&v"(ac3)                     \
          : "v"(aP), "v"(W[0]), "v"(W[1]), "v"(W[2]),  "v"(W[3]),              \
            "v"(W[4]), "v"(W[5]), "v"(W[6]),  "v"(W[7]), "v"(W[8]),            \
            "v"(W[9]), "v"(W[10]), "v"(W[11]), "v"(W[12]), "v"(W[13]),         \
            "v"(W[14]), "v"(W[15]));                                           \
        float xsc = X_T;                                                       \
        if (((J) & 3) == 0) { cacc += eeP * 0.6931471805599453f; xsc *= scP; } \
        aP = ((ac0 + ac1) + (ac2 + ac3)) * xsc;                                \
        if (((J) & 3) == 3) {   /* sample post-update alphas, apply next J&3==0 */ \
            float mm;                                                          \
            asm volatile(                                                      \
              "s_nop 1\n\t"                                                    \
              "v_max_f32_dpp %0, %1, %1 row_ror:8 row_mask:0xf bank_mask:0xf\n\t"\
              "s_nop 1\n\t"                                                    \
              "v_max_f32_dpp %0, %0, %0 row_ror:4 row_mask:0xf bank_mask:0xf\n\t"\
              "s_nop 1\n\t"                                                    \
              "v_max_f32_dpp %0, %0, %0 quad_perm:[1,0,3,2] row_mask:0xf bank_mask:0xf\n\t"\
              "s_nop 1\n\t"                                                    \
              "v_max_f32_dpp %0, %0, %0 quad_perm:[2,3,0,1] row_mask:0xf bank_mask:0xf\n\t"\
              : "=&v"(mm) : "v"(aP));                                          \
            const int ee = (int)((__float_as_uint(mm) >> 23) & 0xFFu) - 127;   \
            scP = __uint_as_float((unsigned)(127 - ee) << 23);                 \
            eeP = (float)ee;                                                   \
        }                                                                      \
        em_acc    += (to == (TG)) ? (E_T) : 0.f;                               \
        trans_acc += sT[tg_prev * SS + (TG)];                                  \
        tg_prev    = (TG);                                                     \
    }

    const float* qe = pe  + (size_t)(1 + PF) * KTAGS;   // next-block prefetch source
    const int*   qt = tgp + 1 + PF;

    int tb = 1;
    for (; tb + 2 * PF <= TT; tb += PF) {   // tb = 1..1001: steps 1..1008
#pragma unroll
        for (int j = 0; j < PF; ++j) {
            const float E_T = ebuf[j];
            const int   TG  = tbuf[j];
            ebuf[j] = qe[j * KTAGS];        // compile-time offsets; pointer bumped per block
            tbuf[j] = qt[j];
            STEP(j, E_T, TG)
        }
        qe += (size_t)PF * KTAGS; qt += PF;
    }

    // penultimate block: steps 1009..1016, prefetch only 7 (steps 1017..1023)
#pragma unroll
    for (int j = 0; j < PF; ++j) {
        const float E_T = ebuf[j];
        const int   TG  = tbuf[j];
        if (j < PF - 1) { ebuf[j] = qe[j * KTAGS]; tbuf[j] = qt[j]; }
        STEP(j, E_T, TG)
    }

    // tail: steps 1017..1023 from slots 0..6
#pragma unroll
    for (int j = 0; j < PF - 1; ++j) {
        STEP(j, ebuf[j], tbuf[j])
    }
#undef STEP

    // ---------------- epilogue: 16-lane reductions ----------------
    float z  = (to < KTAGS) ? aP * eTstop : 0.f;
    float em = em_acc;
#pragma unroll
    for (int s = 8; s >= 1; s >>= 1) {
        z  += __shfl_xor(z,  s, 16);
        em += __shfl_xor(em, s, 16);
    }
    if (to == 0) {
        const float logZ = cacc + __logf(z);
        const float gold = gold0 + em + trans_acc + sT[tg_prev * SS + (SS - 1)];
        out_per_b[b] = logZ - gold;
    }
}

// Deterministic mean over B values (double accumulation).
__global__ __launch_bounds__(256)
void reduce_mean_kernel(const float* __restrict__ v, float* __restrict__ out, int n)
{
    __shared__ double sbuf[256];
    double s = 0.0;
    for (int i = threadIdx.x; i < n; i += 256) s += (double)v[i];
    sbuf[threadIdx.x] = s;
    __syncthreads();
    for (int k = 128; k > 0; k >>= 1) {
        if ((int)threadIdx.x < k) sbuf[threadIdx.x] += sbuf[threadIdx.x + k];
        __syncthreads();
    }
    if (threadIdx.x == 0) out[0] = (float)(sbuf[0] / (double)n);
}

extern "C" void kernel_launch(void* const* d_in, const int* in_sizes, int n_in,
                              void* d_out, int out_size, void* d_ws, size_t ws_size,
                              hipStream_t stream)
{
    const float* e    = (const float*)d_in[0];
    const float* Tmat = (const float*)d_in[1];
    const int*   tags = (const int*)d_in[2];
    // d_in[3] = mask: all-true in this problem; kernel implements the all-true path.

    float* ws  = (float*)d_ws;       // BB floats of scratch
    float* out = (float*)d_out;

    crf_scan_kernel<<<BB / GPW, 64, 0, stream>>>(e, Tmat, tags, ws);
    reduce_mean_kernel<<<1, 256, 0, stream>>>(ws, out, BB);
}